// Round 1
// baseline (293.935 us; speedup 1.0000x reference)
//
#include <hip/hip_runtime.h>

typedef __bf16 bf16;
typedef bf16 bf16x8 __attribute__((ext_vector_type(8)));
typedef bf16 bf16x4 __attribute__((ext_vector_type(4)));
typedef float f32x4 __attribute__((ext_vector_type(4)));

#define BB 8
#define NN 2048
#define MM 4096
#define NHEAD 4

// ---------------------------------------------------------------------------
// Weight prep: W[k][n] f32 -> Wt[n][k] bf16  (4 matrices in one launch)
// ---------------------------------------------------------------------------
__global__ __launch_bounds__(256) void prep_wt(
    const float* W0, const float* W1, const float* W2, const float* W3,
    bf16* T0, bf16* T1, bf16* T2, bf16* T3) {
  const float* W; bf16* T;
  switch (blockIdx.y) {
    case 0:  W = W0; T = T0; break;
    case 1:  W = W1; T = T1; break;
    case 2:  W = W2; T = T2; break;
    default: W = W3; T = T3; break;
  }
  int n = blockIdx.x, k = threadIdx.x;
  T[n * 256 + k] = (bf16)W[k * 256 + n];
}

// ---------------------------------------------------------------------------
// GEMM: C[R][256] = A[R][256] @ W[256][256] + bias, W given as Wt[n][k] bf16.
// Tile 128x128, BK=64, 4 waves each owning 64x64. XOR-swizzled LDS.
// ---------------------------------------------------------------------------
template<int A_IS_F32, int C_IS_F32>
__global__ __launch_bounds__(256) void gemm_bias(
    const void* Aptr, const bf16* Wt, const float* bias, bf16* Cb, float* Cf) {
  __shared__ bf16 As[128 * 64];
  __shared__ bf16 Bs[128 * 64];
  const int t = threadIdx.x;
  const int lane = t & 63, wid = t >> 6;
  const int l15 = lane & 15, lhi = lane >> 4, l7 = lane & 7;
  const int row0 = blockIdx.x * 128, col0 = blockIdx.y * 128;
  const int wm = (wid >> 1) * 64, wn = (wid & 1) * 64;

  f32x4 zero4 = {0.f, 0.f, 0.f, 0.f};
  f32x4 acc[4][4];
#pragma unroll
  for (int i = 0; i < 4; ++i)
#pragma unroll
    for (int j = 0; j < 4; ++j) acc[i][j] = zero4;

  for (int k0 = 0; k0 < 256; k0 += 64) {
    __syncthreads();
    if (A_IS_F32) {
      const float* Af = (const float*)Aptr;
#pragma unroll
      for (int i = 0; i < 8; ++i) {
        int idx = t + i * 256;          // 2048 float4 chunks
        int m = idx >> 4, c4 = idx & 15;
        f32x4 v = *(const f32x4*)(Af + (size_t)(row0 + m) * 256 + k0 + c4 * 4);
        bf16x4 bv;
#pragma unroll
        for (int j = 0; j < 4; ++j) bv[j] = (bf16)v[j];
        *(bf16x4*)((char*)As + m * 128 + ((c4 * 8) ^ ((m & 7) << 4))) = bv;
      }
    } else {
      const bf16* Ab = (const bf16*)Aptr;
#pragma unroll
      for (int i = 0; i < 4; ++i) {
        int idx = t + i * 256;          // 1024 16B chunks
        int m = idx >> 3, c = idx & 7;
        bf16x8 v = *(const bf16x8*)(Ab + (size_t)(row0 + m) * 256 + k0 + c * 8);
        *(bf16x8*)((char*)As + m * 128 + ((c * 16) ^ ((m & 7) << 4))) = v;
      }
    }
#pragma unroll
    for (int i = 0; i < 4; ++i) {
      int idx = t + i * 256;
      int n = idx >> 3, c = idx & 7;
      bf16x8 v = *(const bf16x8*)(Wt + (size_t)(col0 + n) * 256 + k0 + c * 8);
      *(bf16x8*)((char*)Bs + n * 128 + ((c * 16) ^ ((n & 7) << 4))) = v;
    }
    __syncthreads();
#pragma unroll
    for (int kh = 0; kh < 2; ++kh) {
      bf16x8 a[4], b[4];
#pragma unroll
      for (int mi = 0; mi < 4; ++mi) {
        int row = wm + mi * 16 + l15;   // row&7 == l7
        a[mi] = *(const bf16x8*)((char*)As + row * 128 + ((kh * 64 + lhi * 16) ^ (l7 << 4)));
      }
#pragma unroll
      for (int ni = 0; ni < 4; ++ni) {
        int row = wn + ni * 16 + l15;
        b[ni] = *(const bf16x8*)((char*)Bs + row * 128 + ((kh * 64 + lhi * 16) ^ (l7 << 4)));
      }
#pragma unroll
      for (int mi = 0; mi < 4; ++mi)
#pragma unroll
        for (int ni = 0; ni < 4; ++ni)
          acc[mi][ni] = __builtin_amdgcn_mfma_f32_16x16x32_bf16(a[mi], b[ni], acc[mi][ni], 0, 0, 0);
    }
  }
#pragma unroll
  for (int mi = 0; mi < 4; ++mi)
#pragma unroll
    for (int ni = 0; ni < 4; ++ni) {
      int n = col0 + wn + ni * 16 + l15;
      float bvv = bias[n];
#pragma unroll
      for (int r = 0; r < 4; ++r) {
        size_t mrow = (size_t)(row0 + wm + mi * 16 + lhi * 4 + r);
        float val = acc[mi][ni][r] + bvv;
        if (C_IS_F32) Cf[mrow * 256 + n] = val;
        else          Cb[mrow * 256 + n] = (bf16)val;
      }
    }
}

// ---------------------------------------------------------------------------
// V transpose: v[b*M+m][h*64+d] -> vt[(b*H+h)*64+d][m]   (bf16)
// ---------------------------------------------------------------------------
__global__ __launch_bounds__(256) void transpose_v(const bf16* v, bf16* vt) {
  __shared__ bf16 tile[64][72];        // 144B row stride, 16B aligned
  const int t = threadIdx.x;
  const int bh = blockIdx.y, b = bh >> 2, h = bh & 3;
  const int m0 = blockIdx.x * 64;
#pragma unroll
  for (int i = 0; i < 2; ++i) {
    int idx = t + i * 256;
    int r = idx >> 3, c = idx & 7;
    bf16x8 val = *(const bf16x8*)(v + (size_t)(b * MM + m0 + r) * 256 + h * 64 + c * 8);
    *(bf16x8*)&tile[r][c * 8] = val;
  }
  __syncthreads();
#pragma unroll
  for (int i = 0; i < 2; ++i) {
    int idx = t + i * 256;
    int d = idx >> 3, c = idx & 7;
    bf16x8 o;
#pragma unroll
    for (int j = 0; j < 8; ++j) o[j] = tile[c * 8 + j][d];
    *(bf16x8*)(vt + (size_t)(bh * 64 + d) * MM + m0 + c * 8) = o;
  }
}

// ---------------------------------------------------------------------------
// Flash cross-attention. Block = (qtile of 64 rows) x (b,h). 4 waves,
// each wave owns 16 q-rows. KVBLK=64 staged in swizzled LDS.
// ---------------------------------------------------------------------------
__global__ __launch_bounds__(256) void attn_kernel(
    const bf16* q, const bf16* k, const bf16* vt, bf16* ao) {
  __shared__ bf16 Klds[64 * 64];
  __shared__ bf16 Vlds[64 * 64];       // holds V^T chunk: [d][m]
  __shared__ bf16 Plds[4][16 * 64];    // per-wave P
  const int t = threadIdx.x;
  const int lane = t & 63, wid = t >> 6;
  const int l15 = lane & 15, lhi = lane >> 4, l7 = lane & 7;
  const int bh = blockIdx.y, b = bh >> 2, h = bh & 3;
  const int qtile = blockIdx.x;
  const float L2E = 1.44269504088896f;

  // Q fragments (held for the whole kernel)
  bf16x8 qa[2];
  {
    size_t qrow = (size_t)(b * NN + qtile * 64 + wid * 16 + l15);
#pragma unroll
    for (int kh = 0; kh < 2; ++kh)
      qa[kh] = *(const bf16x8*)(q + qrow * 256 + h * 64 + kh * 32 + lhi * 8);
  }

  f32x4 zero4 = {0.f, 0.f, 0.f, 0.f};
  f32x4 oacc[4];
#pragma unroll
  for (int f = 0; f < 4; ++f) oacc[f] = zero4;
  float mrun[4], lrun[4];
#pragma unroll
  for (int r = 0; r < 4; ++r) { mrun[r] = -1e30f; lrun[r] = 0.f; }

  bf16* Pw = &Plds[wid][0];

  for (int kv0 = 0; kv0 < MM; kv0 += 64) {
    __syncthreads();
#pragma unroll
    for (int i = 0; i < 2; ++i) {
      int idx = t + i * 256;
      int r = idx >> 3, c = idx & 7;
      bf16x8 kvv = *(const bf16x8*)(k + (size_t)(b * MM + kv0 + r) * 256 + h * 64 + c * 8);
      *(bf16x8*)((char*)Klds + r * 128 + ((c * 16) ^ ((r & 7) << 4))) = kvv;
      bf16x8 vvv = *(const bf16x8*)(vt + (size_t)(bh * 64 + r) * MM + kv0 + c * 8);
      *(bf16x8*)((char*)Vlds + r * 128 + ((c * 16) ^ ((r & 7) << 4))) = vvv;
    }
    __syncthreads();

    // S = Q K^T * 0.125  (16 x 64 per wave)
    f32x4 sacc[4] = {zero4, zero4, zero4, zero4};
#pragma unroll
    for (int kh = 0; kh < 2; ++kh) {
#pragma unroll
      for (int f = 0; f < 4; ++f) {
        int row = f * 16 + l15;
        bf16x8 kb = *(const bf16x8*)((char*)Klds + row * 128 + ((kh * 64 + lhi * 16) ^ (l7 << 4)));
        sacc[f] = __builtin_amdgcn_mfma_f32_16x16x32_bf16(qa[kh], kb, sacc[f], 0, 0, 0);
      }
    }

    // online softmax (fp32), rows live on 16-lane groups
    float alpha[4], rs[4];
#pragma unroll
    for (int r = 0; r < 4; ++r) {
      float mx = fmaxf(fmaxf(sacc[0][r], sacc[1][r]), fmaxf(sacc[2][r], sacc[3][r])) * 0.125f;
#pragma unroll
      for (int msk = 1; msk < 16; msk <<= 1) mx = fmaxf(mx, __shfl_xor(mx, msk));
      float mnew = fmaxf(mrun[r], mx);
      alpha[r] = exp2f((mrun[r] - mnew) * L2E);
      mrun[r] = mnew;
      rs[r] = 0.f;
    }
#pragma unroll
    for (int f = 0; f < 4; ++f)
#pragma unroll
      for (int r = 0; r < 4; ++r) {
        float p = exp2f((sacc[f][r] * 0.125f - mrun[r]) * L2E);
        rs[r] += p;
        int ql = lhi * 4 + r;
        *(bf16*)((char*)Pw + ql * 128 + ((f * 32 + l15 * 2) ^ ((ql & 7) << 4))) = (bf16)p;
      }
#pragma unroll
    for (int r = 0; r < 4; ++r) {
#pragma unroll
      for (int msk = 1; msk < 16; msk <<= 1) rs[r] += __shfl_xor(rs[r], msk);
      lrun[r] = lrun[r] * alpha[r] + rs[r];
    }
#pragma unroll
    for (int f = 0; f < 4; ++f)
#pragma unroll
      for (int r = 0; r < 4; ++r) oacc[f][r] *= alpha[r];

    // O += P V  (A = P from LDS, B = V^T rows)
#pragma unroll
    for (int mh = 0; mh < 2; ++mh) {
      bf16x8 pa = *(const bf16x8*)((char*)Pw + l15 * 128 + ((mh * 64 + lhi * 16) ^ (l7 << 4)));
#pragma unroll
      for (int f = 0; f < 4; ++f) {
        int row = f * 16 + l15;         // d-row of V^T
        bf16x8 vb = *(const bf16x8*)((char*)Vlds + row * 128 + ((mh * 64 + lhi * 16) ^ (l7 << 4)));
        oacc[f] = __builtin_amdgcn_mfma_f32_16x16x32_bf16(pa, vb, oacc[f], 0, 0, 0);
      }
    }
  }

  // epilogue: normalize and store bf16
  float inv[4];
#pragma unroll
  for (int r = 0; r < 4; ++r) inv[r] = 1.f / lrun[r];
#pragma unroll
  for (int f = 0; f < 4; ++f)
#pragma unroll
    for (int r = 0; r < 4; ++r) {
      int nrow = qtile * 64 + wid * 16 + lhi * 4 + r;
      int col = h * 64 + f * 16 + l15;
      ao[(size_t)(b * NN + nrow) * 256 + col] = (bf16)(oacc[f][r] * inv[r]);
    }
}

// ---------------------------------------------------------------------------
extern "C" void kernel_launch(void* const* d_in, const int* in_sizes, int n_in,
                              void* d_out, int out_size, void* d_ws, size_t ws_size,
                              hipStream_t stream) {
  const float* nuc = (const float*)d_in[0];
  const float* ele = (const float*)d_in[1];
  const float* Wq  = (const float*)d_in[2];
  const float* bq  = (const float*)d_in[3];
  const float* Wk  = (const float*)d_in[4];
  const float* bk  = (const float*)d_in[5];
  const float* Wv  = (const float*)d_in[6];
  const float* bv  = (const float*)d_in[7];
  const float* Wo  = (const float*)d_in[8];
  const float* bo  = (const float*)d_in[9];
  float* out = (float*)d_out;
  char* ws = (char*)d_ws;

  bf16* wtq = (bf16*)(ws + 0);                    // 4 x 128KB transposed weights
  bf16* wtk = (bf16*)(ws + 131072);
  bf16* wtv = (bf16*)(ws + 262144);
  bf16* wto = (bf16*)(ws + 393216);
  bf16* qws = (bf16*)(ws + 524288);               // 8.39 MB
  bf16* kws = (bf16*)(ws + 8912896);              // 16.78 MB
  bf16* vws = (bf16*)(ws + 25690112);             // 16.78 MB
  bf16* vtw = (bf16*)(ws + 42467328);             // 16.78 MB
  bf16* aow = (bf16*)(ws + 59244544);             // 8.39 MB

  prep_wt<<<dim3(256, 4), 256, 0, stream>>>(Wq, Wk, Wv, Wo, wtq, wtk, wtv, wto);

  gemm_bias<1, 0><<<dim3(128, 2), 256, 0, stream>>>(nuc, wtq, bq, qws, nullptr);
  gemm_bias<1, 0><<<dim3(256, 2), 256, 0, stream>>>(ele, wtk, bk, kws, nullptr);
  gemm_bias<1, 0><<<dim3(256, 2), 256, 0, stream>>>(ele, wtv, bv, vws, nullptr);

  transpose_v<<<dim3(64, 32), 256, 0, stream>>>(vws, vtw);

  attn_kernel<<<dim3(32, 32), 256, 0, stream>>>(qws, kws, vtw, aow);

  gemm_bias<0, 1><<<dim3(128, 2), 256, 0, stream>>>(aow, wto, bo, nullptr, out);
}